// Round 2
// baseline (596.663 us; speedup 1.0000x reference)
//
#include <hip/hip_runtime.h>
#include <cstdint>
#include <cstddef>

#define NN 50000
#define EE 800000
#define DD 128

// ---------------- ws layout (bytes) ----------------
// deg      [N] int      @ 0        (200000)
// cursor   [N] int      @ 200000   (200000)   -- memset with deg in one shot
// row_ptr  [N+1] int    @ 400000   (200004)
// csr_src  [E] int      @ 600064   (3200000)
// dinv     [N] float    @ 3800064  (200000)
// flag     [1] int      @ 4000064  (4)
// H        [N*D] float  @ 4000256  (25600000)
// total: 29,600,256 bytes

__device__ __forceinline__ void fma4(float4& a, float s, const float4& v) {
    a.x = fmaf(s, v.x, a.x);
    a.y = fmaf(s, v.y, a.y);
    a.z = fmaf(s, v.z, a.z);
    a.w = fmaf(s, v.w, a.w);
}

__device__ __forceinline__ int ld_idx(const int* __restrict__ p, long long i, int mode64) {
    // mode64: data is int64 little-endian, value fits in low dword
    return mode64 ? p[2 * i] : p[(size_t)i];
}

// Detect whether edge_index arrived as int64 (high dwords all zero) or int32.
__global__ void probe_kernel(const int* __restrict__ ei, int* __restrict__ flag) {
    int t = threadIdx.x;
    int v = ei[2 * t + 1];                 // odd dwords of first 64 qwords
    unsigned long long b = __ballot(v != 0);
    if (t == 0) *flag = (b == 0ull) ? 1 : 0;
}

__global__ void count_kernel(const int* __restrict__ ei, const int* __restrict__ flag,
                             int* __restrict__ deg) {
    int e = blockIdx.x * 256 + threadIdx.x;
    if (e >= EE) return;
    int m = *flag;
    int d = ld_idx(ei, (long long)EE + e, m);
    atomicAdd(&deg[d], 1);
}

// Single-block exclusive scan of deg -> row_ptr, plus dinv = rsqrt(deg+1).
__global__ void scan_kernel(const int* __restrict__ deg, int* __restrict__ row_ptr,
                            float* __restrict__ dinv) {
    __shared__ int part[256];
    int t = threadIdx.x;
    const int CH = (NN + 255) / 256;   // 196
    int base = t * CH;
    int s = 0;
    for (int i = 0; i < CH; i++) {
        int idx = base + i;
        if (idx < NN) s += deg[idx];
    }
    part[t] = s;
    __syncthreads();
    for (int off = 1; off < 256; off <<= 1) {
        int v = 0;
        if (t >= off) v = part[t - off];
        __syncthreads();
        part[t] += v;
        __syncthreads();
    }
    int run = (t == 0) ? 0 : part[t - 1];
    for (int i = 0; i < CH; i++) {
        int idx = base + i;
        if (idx < NN) {
            row_ptr[idx] = run;
            int d = deg[idx];
            run += d;
            dinv[idx] = rsqrtf((float)(d + 1));   // +1 = self loop; always > 0
        }
    }
    if (t == 255) row_ptr[NN] = run;
}

__global__ void fill_kernel(const int* __restrict__ ei, const int* __restrict__ flag,
                            const int* __restrict__ row_ptr, int* __restrict__ cursor,
                            int* __restrict__ csr_src) {
    int e = blockIdx.x * 256 + threadIdx.x;
    if (e >= EE) return;
    int m = *flag;
    int sv = ld_idx(ei, (long long)e, m);
    int dv = ld_idx(ei, (long long)EE + e, m);
    int pos = row_ptr[dv] + atomicAdd(&cursor[dv], 1);
    csr_src[pos] = sv;
}

// H = rmsnorm(X, g) @ W.  Block: 256 thr, 32 rows.  xn staged in LDS (16KB).
// Thread (tc=t&31, tr=t>>5) computes rows r0..r0+3, cols 4*tc..4*tc+3.
__global__ __launch_bounds__(256) void rmsnorm_gemm_kernel(
        const float* __restrict__ X, const float* __restrict__ W,
        const float* __restrict__ g, float* __restrict__ H) {
    __shared__ float xn[32][DD];
    int t = threadIdx.x;
    int row0 = blockIdx.x * 32;

    // ---- stage + rmsnorm: thread t handles row t>>3, 16 floats at (t&7)*16
    int r = t >> 3, part = t & 7;
    int row = row0 + r;
    float4 v0 = {0,0,0,0}, v1 = v0, v2 = v0, v3 = v0;
    float ss = 0.f;
    if (row < NN) {
        const float4* xr = (const float4*)(X + (size_t)row * DD) + part * 4;
        v0 = xr[0]; v1 = xr[1]; v2 = xr[2]; v3 = xr[3];
        ss = v0.x*v0.x + v0.y*v0.y + v0.z*v0.z + v0.w*v0.w
           + v1.x*v1.x + v1.y*v1.y + v1.z*v1.z + v1.w*v1.w
           + v2.x*v2.x + v2.y*v2.y + v2.z*v2.z + v2.w*v2.w
           + v3.x*v3.x + v3.y*v3.y + v3.z*v3.z + v3.w*v3.w;
    }
    // 8 lanes per row, consecutive -> xor reduce within wave
    ss += __shfl_xor(ss, 1);
    ss += __shfl_xor(ss, 2);
    ss += __shfl_xor(ss, 4);
    float sc = rsqrtf(ss * (1.0f / DD) + 1e-6f);

    const float4* g4 = (const float4*)g + part * 4;
    float4* xrow = (float4*)(&xn[r][0]) + part * 4;
    {
        float4 q, gq;
        gq = g4[0]; q.x = v0.x*sc*gq.x; q.y = v0.y*sc*gq.y; q.z = v0.z*sc*gq.z; q.w = v0.w*sc*gq.w; xrow[0] = q;
        gq = g4[1]; q.x = v1.x*sc*gq.x; q.y = v1.y*sc*gq.y; q.z = v1.z*sc*gq.z; q.w = v1.w*sc*gq.w; xrow[1] = q;
        gq = g4[2]; q.x = v2.x*sc*gq.x; q.y = v2.y*sc*gq.y; q.z = v2.z*sc*gq.z; q.w = v2.w*sc*gq.w; xrow[2] = q;
        gq = g4[3]; q.x = v3.x*sc*gq.x; q.y = v3.y*sc*gq.y; q.z = v3.z*sc*gq.z; q.w = v3.w*sc*gq.w; xrow[3] = q;
    }
    __syncthreads();

    // ---- gemm: W read from global (64KB, L2-resident)
    int tc = t & 31, tr = t >> 5;
    int r0 = tr * 4;
    const float4* W4 = (const float4*)W;   // [k][32] float4
    float4 a0 = {0,0,0,0}, a1 = a0, a2 = a0, a3 = a0;
    #pragma unroll 4
    for (int k = 0; k < DD; k += 4) {
        float4 w0 = W4[(k+0)*32 + tc];
        float4 w1 = W4[(k+1)*32 + tc];
        float4 w2 = W4[(k+2)*32 + tc];
        float4 w3 = W4[(k+3)*32 + tc];
        float4 x0 = *(const float4*)&xn[r0+0][k];
        float4 x1 = *(const float4*)&xn[r0+1][k];
        float4 x2 = *(const float4*)&xn[r0+2][k];
        float4 x3 = *(const float4*)&xn[r0+3][k];
        fma4(a0, x0.x, w0); fma4(a0, x0.y, w1); fma4(a0, x0.z, w2); fma4(a0, x0.w, w3);
        fma4(a1, x1.x, w0); fma4(a1, x1.y, w1); fma4(a1, x1.z, w2); fma4(a1, x1.w, w3);
        fma4(a2, x2.x, w0); fma4(a2, x2.y, w1); fma4(a2, x2.z, w2); fma4(a2, x2.w, w3);
        fma4(a3, x3.x, w0); fma4(a3, x3.y, w1); fma4(a3, x3.z, w2); fma4(a3, x3.w, w3);
    }
    int rb = row0 + r0;
    if (rb + 0 < NN) ((float4*)(H + (size_t)(rb+0)*DD))[tc] = a0;
    if (rb + 1 < NN) ((float4*)(H + (size_t)(rb+1)*DD))[tc] = a1;
    if (rb + 2 < NN) ((float4*)(H + (size_t)(rb+2)*DD))[tc] = a2;
    if (rb + 3 < NN) ((float4*)(H + (size_t)(rb+3)*DD))[tc] = a3;
}

// out[n] = relu( sum_{e:dst=n} H[src]*dinv[src]*dinv[n] + H[n]*dinv[n]^2 + b )
// One wave per node; halves of the wave take alternate edges; 32 lanes x float4.
__global__ __launch_bounds__(256) void aggregate_kernel(
        const float* __restrict__ Hm, const float* __restrict__ dinv,
        const int* __restrict__ row_ptr, const int* __restrict__ csr_src,
        const float* __restrict__ b, float* __restrict__ out) {
    int wv = threadIdx.x >> 6;
    int lane = threadIdx.x & 63;
    int n = blockIdx.x * 4 + wv;          // grid = N/4 exactly
    int half = lane >> 5;
    int tc = lane & 31;
    const float4* H4 = (const float4*)Hm;
    float dn = dinv[n];
    float4 acc = {0,0,0,0};
    if (half == 0) {                      // self loop + bias, added once
        float4 hv = H4[(size_t)n * 32 + tc];
        float4 bv = ((const float4*)b)[tc];
        float w = dn * dn;
        acc.x = fmaf(hv.x, w, bv.x);
        acc.y = fmaf(hv.y, w, bv.y);
        acc.z = fmaf(hv.z, w, bv.z);
        acc.w = fmaf(hv.w, w, bv.w);
    }
    int start = row_ptr[n], end = row_ptr[n + 1];
    for (int e = start + half; e < end; e += 2) {
        int s = csr_src[e];
        float w = dinv[s] * dn;
        float4 hv = H4[(size_t)s * 32 + tc];
        fma4(acc, w, hv);
    }
    acc.x += __shfl_xor(acc.x, 32);
    acc.y += __shfl_xor(acc.y, 32);
    acc.z += __shfl_xor(acc.z, 32);
    acc.w += __shfl_xor(acc.w, 32);
    if (half == 0) {
        acc.x = fmaxf(acc.x, 0.f);
        acc.y = fmaxf(acc.y, 0.f);
        acc.z = fmaxf(acc.z, 0.f);
        acc.w = fmaxf(acc.w, 0.f);
        ((float4*)(out + (size_t)n * DD))[tc] = acc;
    }
}

extern "C" void kernel_launch(void* const* d_in, const int* in_sizes, int n_in,
                              void* d_out, int out_size, void* d_ws, size_t ws_size,
                              hipStream_t stream) {
    (void)in_sizes; (void)n_in; (void)out_size; (void)ws_size;
    const float* x  = (const float*)d_in[0];
    const int*   ei = (const int*)d_in[1];
    const float* W1 = (const float*)d_in[2];
    const float* b1 = (const float*)d_in[3];
    const float* g1 = (const float*)d_in[4];
    const float* W2 = (const float*)d_in[5];
    const float* b2 = (const float*)d_in[6];
    const float* g2 = (const float*)d_in[7];
    const float* W3 = (const float*)d_in[8];
    const float* b3 = (const float*)d_in[9];
    const float* g3 = (const float*)d_in[10];
    float* out = (float*)d_out;

    char* wsb = (char*)d_ws;
    int*   deg     = (int*)(wsb + 0);
    int*   cursor  = (int*)(wsb + 200000);
    int*   row_ptr = (int*)(wsb + 400000);
    int*   csr_src = (int*)(wsb + 600064);
    float* dinv    = (float*)(wsb + 3800064);
    int*   flag    = (int*)(wsb + 4000064);
    float* Hb      = (float*)(wsb + 4000256);

    // zero deg + cursor in one shot (contiguous)
    hipMemsetAsync(deg, 0, 400000, stream);

    probe_kernel<<<1, 64, 0, stream>>>(ei, flag);
    count_kernel<<<(EE + 255) / 256, 256, 0, stream>>>(ei, flag, deg);
    scan_kernel<<<1, 256, 0, stream>>>(deg, row_ptr, dinv);
    fill_kernel<<<(EE + 255) / 256, 256, 0, stream>>>(ei, flag, row_ptr, cursor, csr_src);

    const int gemm_grid = (NN + 31) / 32;   // 1563
    const int agg_grid  = NN / 4;           // 12500

    // layer 1: x -> H -> out (out doubles as ping buffer)
    rmsnorm_gemm_kernel<<<gemm_grid, 256, 0, stream>>>(x, W1, g1, Hb);
    aggregate_kernel<<<agg_grid, 256, 0, stream>>>(Hb, dinv, row_ptr, csr_src, b1, out);
    // layer 2: out -> H -> out
    rmsnorm_gemm_kernel<<<gemm_grid, 256, 0, stream>>>(out, W2, g2, Hb);
    aggregate_kernel<<<agg_grid, 256, 0, stream>>>(Hb, dinv, row_ptr, csr_src, b2, out);
    // layer 3: out -> H -> d_out
    rmsnorm_gemm_kernel<<<gemm_grid, 256, 0, stream>>>(out, W3, g3, Hb);
    aggregate_kernel<<<agg_grid, 256, 0, stream>>>(Hb, dinv, row_ptr, csr_src, b3, out);
}

// Round 3
// 477.199 us; speedup vs baseline: 1.2503x; 1.2503x over previous
//
#include <hip/hip_runtime.h>
#include <cstdint>
#include <cstddef>

#define NN 50000
#define EE 800000
#define DD 128
#define NBLK 196   // ceil(NN/256)

// ---------------- ws layout (bytes) ----------------
// deg      [N] int      @ 0        (200000)  -- count target; zeroed by scatter_scan; reused as fill cursor
// bsum     [NBLK] int   @ 200000   (784)
// boff     [NBLK+1] int @ 200832   (788)
// row_ptr  [N+1] int    @ 400000   (200004)
// csr_src  [E] int      @ 600064   (3200000)
// dinv     [N] float    @ 3800064  (200000)
// flag     [1] int      @ 4000064  (4)
// H        [N*D] float  @ 4000256  (25600000)
// total: 29,600,256 bytes

__device__ __forceinline__ void fma4(float4& a, float s, const float4& v) {
    a.x = fmaf(s, v.x, a.x);
    a.y = fmaf(s, v.y, a.y);
    a.z = fmaf(s, v.z, a.z);
    a.w = fmaf(s, v.w, a.w);
}

__device__ __forceinline__ int ld_idx(const int* __restrict__ p, long long i, int mode64) {
    // mode64: data is int64 little-endian, value fits in low dword
    return mode64 ? p[2 * i] : p[(size_t)i];
}

// Detect whether edge_index arrived as int64 (high dwords all zero) or int32.
__global__ void probe_kernel(const int* __restrict__ ei, int* __restrict__ flag) {
    int t = threadIdx.x;
    int v = ei[2 * t + 1];                 // odd dwords of first 64 qwords
    unsigned long long b = __ballot(v != 0);
    if (t == 0) *flag = (b == 0ull) ? 1 : 0;
}

__global__ void count_kernel(const int* __restrict__ ei, const int* __restrict__ flag,
                             int* __restrict__ deg) {
    int e = blockIdx.x * 256 + threadIdx.x;
    if (e >= EE) return;
    int m = *flag;
    int d = ld_idx(ei, (long long)EE + e, m);
    atomicAdd(&deg[d], 1);
}

// ---- decoupled scan: per-block sums -> scan of sums -> per-chunk scan ----
__global__ __launch_bounds__(256) void partial_kernel(const int* __restrict__ deg,
                                                      int* __restrict__ bsum) {
    int idx = blockIdx.x * 256 + threadIdx.x;
    int v = (idx < NN) ? deg[idx] : 0;
    for (int off = 1; off < 64; off <<= 1) v += __shfl_xor(v, off);
    __shared__ int ws[4];
    if ((threadIdx.x & 63) == 0) ws[threadIdx.x >> 6] = v;
    __syncthreads();
    if (threadIdx.x == 0) bsum[blockIdx.x] = ws[0] + ws[1] + ws[2] + ws[3];
}

__global__ __launch_bounds__(256) void bscan_kernel(const int* __restrict__ bsum,
                                                    int* __restrict__ boff) {
    __shared__ int sh[256];
    int t = threadIdx.x;
    sh[t] = (t < NBLK) ? bsum[t] : 0;
    __syncthreads();
    for (int off = 1; off < 256; off <<= 1) {
        int u = (t >= off) ? sh[t - off] : 0;
        __syncthreads();
        sh[t] += u;
        __syncthreads();
    }
    if (t <= NBLK) boff[t] = (t == 0) ? 0 : sh[t - 1];   // exclusive; boff[NBLK] = total
}

__global__ __launch_bounds__(256) void scatter_scan_kernel(
        int* __restrict__ deg, const int* __restrict__ boff,
        int* __restrict__ row_ptr, float* __restrict__ dinv) {
    __shared__ int sh[256];
    int t = threadIdx.x;
    int idx = blockIdx.x * 256 + t;
    int v = (idx < NN) ? deg[idx] : 0;
    sh[t] = v;
    __syncthreads();
    for (int off = 1; off < 256; off <<= 1) {
        int u = (t >= off) ? sh[t - off] : 0;
        __syncthreads();
        sh[t] += u;
        __syncthreads();
    }
    if (idx < NN) {
        row_ptr[idx] = boff[blockIdx.x] + sh[t] - v;   // exclusive prefix
        dinv[idx] = rsqrtf((float)(v + 1));            // +1 = self loop; always > 0
        deg[idx] = 0;                                  // becomes fill's cursor
    }
    if (idx == 0) row_ptr[NN] = boff[NBLK];
}

__global__ void fill_kernel(const int* __restrict__ ei, const int* __restrict__ flag,
                            const int* __restrict__ row_ptr, int* __restrict__ cursor,
                            int* __restrict__ csr_src) {
    int e = blockIdx.x * 256 + threadIdx.x;
    if (e >= EE) return;
    int m = *flag;
    int sv = ld_idx(ei, (long long)e, m);
    int dv = ld_idx(ei, (long long)EE + e, m);
    int pos = row_ptr[dv] + atomicAdd(&cursor[dv], 1);
    csr_src[pos] = sv;
}

// H = rmsnorm(X, g) @ W.  Block: 256 thr, 32 rows.  xn staged in LDS (16KB).
// Thread (tc=t&31, tr=t>>5) computes rows r0..r0+3, cols 4*tc..4*tc+3.
__global__ __launch_bounds__(256) void rmsnorm_gemm_kernel(
        const float* __restrict__ X, const float* __restrict__ W,
        const float* __restrict__ g, float* __restrict__ H) {
    __shared__ float xn[32][DD];
    int t = threadIdx.x;
    int row0 = blockIdx.x * 32;

    // ---- stage + rmsnorm: thread t handles row t>>3, 16 floats at (t&7)*16
    int r = t >> 3, part = t & 7;
    int row = row0 + r;
    float4 v0 = {0,0,0,0}, v1 = v0, v2 = v0, v3 = v0;
    float ss = 0.f;
    if (row < NN) {
        const float4* xr = (const float4*)(X + (size_t)row * DD) + part * 4;
        v0 = xr[0]; v1 = xr[1]; v2 = xr[2]; v3 = xr[3];
        ss = v0.x*v0.x + v0.y*v0.y + v0.z*v0.z + v0.w*v0.w
           + v1.x*v1.x + v1.y*v1.y + v1.z*v1.z + v1.w*v1.w
           + v2.x*v2.x + v2.y*v2.y + v2.z*v2.z + v2.w*v2.w
           + v3.x*v3.x + v3.y*v3.y + v3.z*v3.z + v3.w*v3.w;
    }
    // 8 lanes per row, consecutive -> xor reduce within wave
    ss += __shfl_xor(ss, 1);
    ss += __shfl_xor(ss, 2);
    ss += __shfl_xor(ss, 4);
    float sc = rsqrtf(ss * (1.0f / DD) + 1e-6f);

    const float4* g4 = (const float4*)g + part * 4;
    float4* xrow = (float4*)(&xn[r][0]) + part * 4;
    {
        float4 q, gq;
        gq = g4[0]; q.x = v0.x*sc*gq.x; q.y = v0.y*sc*gq.y; q.z = v0.z*sc*gq.z; q.w = v0.w*sc*gq.w; xrow[0] = q;
        gq = g4[1]; q.x = v1.x*sc*gq.x; q.y = v1.y*sc*gq.y; q.z = v1.z*sc*gq.z; q.w = v1.w*sc*gq.w; xrow[1] = q;
        gq = g4[2]; q.x = v2.x*sc*gq.x; q.y = v2.y*sc*gq.y; q.z = v2.z*sc*gq.z; q.w = v2.w*sc*gq.w; xrow[2] = q;
        gq = g4[3]; q.x = v3.x*sc*gq.x; q.y = v3.y*sc*gq.y; q.z = v3.z*sc*gq.z; q.w = v3.w*sc*gq.w; xrow[3] = q;
    }
    __syncthreads();

    // ---- gemm: W read from global (64KB, L2-resident)
    int tc = t & 31, tr = t >> 5;
    int r0 = tr * 4;
    const float4* W4 = (const float4*)W;   // [k][32] float4
    float4 a0 = {0,0,0,0}, a1 = a0, a2 = a0, a3 = a0;
    #pragma unroll 4
    for (int k = 0; k < DD; k += 4) {
        float4 w0 = W4[(k+0)*32 + tc];
        float4 w1 = W4[(k+1)*32 + tc];
        float4 w2 = W4[(k+2)*32 + tc];
        float4 w3 = W4[(k+3)*32 + tc];
        float4 x0 = *(const float4*)&xn[r0+0][k];
        float4 x1 = *(const float4*)&xn[r0+1][k];
        float4 x2 = *(const float4*)&xn[r0+2][k];
        float4 x3 = *(const float4*)&xn[r0+3][k];
        fma4(a0, x0.x, w0); fma4(a0, x0.y, w1); fma4(a0, x0.z, w2); fma4(a0, x0.w, w3);
        fma4(a1, x1.x, w0); fma4(a1, x1.y, w1); fma4(a1, x1.z, w2); fma4(a1, x1.w, w3);
        fma4(a2, x2.x, w0); fma4(a2, x2.y, w1); fma4(a2, x2.z, w2); fma4(a2, x2.w, w3);
        fma4(a3, x3.x, w0); fma4(a3, x3.y, w1); fma4(a3, x3.z, w2); fma4(a3, x3.w, w3);
    }
    int rb = row0 + r0;
    if (rb + 0 < NN) ((float4*)(H + (size_t)(rb+0)*DD))[tc] = a0;
    if (rb + 1 < NN) ((float4*)(H + (size_t)(rb+1)*DD))[tc] = a1;
    if (rb + 2 < NN) ((float4*)(H + (size_t)(rb+2)*DD))[tc] = a2;
    if (rb + 3 < NN) ((float4*)(H + (size_t)(rb+3)*DD))[tc] = a3;
}

// out[n] = relu( sum_{e:dst=n} H[src]*dinv[src]*dinv[n] + H[n]*dinv[n]^2 + b )
// One wave per node; halves of the wave take alternate edges; 32 lanes x float4.
__global__ __launch_bounds__(256) void aggregate_kernel(
        const float* __restrict__ Hm, const float* __restrict__ dinv,
        const int* __restrict__ row_ptr, const int* __restrict__ csr_src,
        const float* __restrict__ b, float* __restrict__ out) {
    int wv = threadIdx.x >> 6;
    int lane = threadIdx.x & 63;
    int n = blockIdx.x * 4 + wv;          // grid = N/4 exactly
    int half = lane >> 5;
    int tc = lane & 31;
    const float4* H4 = (const float4*)Hm;
    float dn = dinv[n];
    float4 acc = {0,0,0,0};
    if (half == 0) {                      // self loop + bias, added once
        float4 hv = H4[(size_t)n * 32 + tc];
        float4 bv = ((const float4*)b)[tc];
        float w = dn * dn;
        acc.x = fmaf(hv.x, w, bv.x);
        acc.y = fmaf(hv.y, w, bv.y);
        acc.z = fmaf(hv.z, w, bv.z);
        acc.w = fmaf(hv.w, w, bv.w);
    }
    int start = row_ptr[n], end = row_ptr[n + 1];
    for (int e = start + half; e < end; e += 2) {
        int s = csr_src[e];
        float w = dinv[s] * dn;
        float4 hv = H4[(size_t)s * 32 + tc];
        fma4(acc, w, hv);
    }
    acc.x += __shfl_xor(acc.x, 32);
    acc.y += __shfl_xor(acc.y, 32);
    acc.z += __shfl_xor(acc.z, 32);
    acc.w += __shfl_xor(acc.w, 32);
    if (half == 0) {
        acc.x = fmaxf(acc.x, 0.f);
        acc.y = fmaxf(acc.y, 0.f);
        acc.z = fmaxf(acc.z, 0.f);
        acc.w = fmaxf(acc.w, 0.f);
        ((float4*)(out + (size_t)n * DD))[tc] = acc;
    }
}

extern "C" void kernel_launch(void* const* d_in, const int* in_sizes, int n_in,
                              void* d_out, int out_size, void* d_ws, size_t ws_size,
                              hipStream_t stream) {
    (void)in_sizes; (void)n_in; (void)out_size; (void)ws_size;
    const float* x  = (const float*)d_in[0];
    const int*   ei = (const int*)d_in[1];
    const float* W1 = (const float*)d_in[2];
    const float* b1 = (const float*)d_in[3];
    const float* g1 = (const float*)d_in[4];
    const float* W2 = (const float*)d_in[5];
    const float* b2 = (const float*)d_in[6];
    const float* g2 = (const float*)d_in[7];
    const float* W3 = (const float*)d_in[8];
    const float* b3 = (const float*)d_in[9];
    const float* g3 = (const float*)d_in[10];
    float* out = (float*)d_out;

    char* wsb = (char*)d_ws;
    int*   deg     = (int*)(wsb + 0);        // doubles as fill cursor
    int*   bsum    = (int*)(wsb + 200000);
    int*   boff    = (int*)(wsb + 200832);
    int*   row_ptr = (int*)(wsb + 400000);
    int*   csr_src = (int*)(wsb + 600064);
    float* dinv    = (float*)(wsb + 3800064);
    int*   flag    = (int*)(wsb + 4000064);
    float* Hb      = (float*)(wsb + 4000256);

    hipMemsetAsync(deg, 0, 200000, stream);

    probe_kernel<<<1, 64, 0, stream>>>(ei, flag);
    count_kernel<<<(EE + 255) / 256, 256, 0, stream>>>(ei, flag, deg);
    partial_kernel<<<NBLK, 256, 0, stream>>>(deg, bsum);
    bscan_kernel<<<1, 256, 0, stream>>>(bsum, boff);
    scatter_scan_kernel<<<NBLK, 256, 0, stream>>>(deg, boff, row_ptr, dinv);
    fill_kernel<<<(EE + 255) / 256, 256, 0, stream>>>(ei, flag, row_ptr, deg, csr_src);

    const int gemm_grid = (NN + 31) / 32;   // 1563
    const int agg_grid  = NN / 4;           // 12500

    // layer 1: x -> H -> out (out doubles as ping buffer)
    rmsnorm_gemm_kernel<<<gemm_grid, 256, 0, stream>>>(x, W1, g1, Hb);
    aggregate_kernel<<<agg_grid, 256, 0, stream>>>(Hb, dinv, row_ptr, csr_src, b1, out);
    // layer 2: out -> H -> out
    rmsnorm_gemm_kernel<<<gemm_grid, 256, 0, stream>>>(out, W2, g2, Hb);
    aggregate_kernel<<<agg_grid, 256, 0, stream>>>(Hb, dinv, row_ptr, csr_src, b2, out);
    // layer 3: out -> H -> d_out
    rmsnorm_gemm_kernel<<<gemm_grid, 256, 0, stream>>>(out, W3, g3, Hb);
    aggregate_kernel<<<agg_grid, 256, 0, stream>>>(Hb, dinv, row_ptr, csr_src, b3, out);
}